// Round 8
// baseline (165.302 us; speedup 1.0000x reference)
//
#include <hip/hip_runtime.h>

typedef __attribute__((ext_vector_type(8))) short short8;
typedef __attribute__((ext_vector_type(16))) float f32x16;
typedef __attribute__((ext_vector_type(4))) unsigned short ushort4v;

#define BN_EPS 1e-5f
#define KOFF 27

static __device__ __forceinline__ unsigned short f2bf(float f) {
  unsigned int u = __float_as_uint(f);
  u += 0x7fffu + ((u >> 16) & 1u);
  return (unsigned short)(u >> 16);
}

static __device__ __forceinline__ float silu_f(float z) {
  return z / (1.f + __expf(-z));
}

static __device__ __forceinline__ void gload_lds16(const void* g, void* l) {
  __builtin_amdgcn_global_load_lds(
      (const __attribute__((address_space(1))) unsigned int*)g,
      (__attribute__((address_space(3))) unsigned int*)l, 16, 0, 0);
}

#define WAITV(n) asm volatile("s_waitcnt vmcnt(" #n ")" ::: "memory")

// ---- time embedding MLP: tp = silu(t) @ Wt + bt; store (1+scale), shift
__global__ void time_mlp(const float* __restrict__ t, const float* __restrict__ Wt,
                         const float* __restrict__ bt,
                         float* __restrict__ scale_eff, float* __restrict__ shift) {
  int tid = blockIdx.x * blockDim.x + threadIdx.x; // 2048 = 16 batches * 128 out
  int bi = tid >> 7, co = tid & 127;
  float acc = bt[co];
  for (int e = 0; e < 256; ++e) {
    float tv = t[bi * 256 + e];
    acc += silu_f(tv) * Wt[e * 128 + co];
  }
  if (co < 64) scale_eff[bi * 64 + co] = 1.f + acc;
  else         shift[bi * 64 + (co - 64)] = acc;
}

// ---- pack W1 and W2 [k, ci, co] (f32) into bf16 MFMA B-fragment order (32x32x16).
// Fragment f = k*8 + ks*2 + cb : lane l elem j <- W[k][ks*16 + (l>>5)*8 + j][cb*32 + (l&31)]
__global__ void pack_w32(const float* __restrict__ W1, const float* __restrict__ W2,
                         unsigned short* __restrict__ Wp1, unsigned short* __restrict__ Wp2) {
  const int tot = KOFF * 4 * 2 * 64 * 8;
  int tid = blockIdx.x * blockDim.x + threadIdx.x;
  const float* W = W1;
  unsigned short* Wp = Wp1;
  if (tid >= tot) { tid -= tot; W = W2; Wp = Wp2; }
  if (tid >= tot) return;
  int j = tid & 7, lane = (tid >> 3) & 63, cb = (tid >> 9) & 1, ks = (tid >> 10) & 3, k = tid >> 12;
  int ci = ks * 16 + (lane >> 5) * 8 + j;
  int co = cb * 32 + (lane & 31);
  Wp[tid] = f2bf(W[(k * 64 + ci) * 64 + co]);
}

// ---- a1 = bf16(silu(bn1(x))), bn1 affine computed inline; tail threads zero row N
__global__ void bn_silu_k(const float* __restrict__ x, const float* __restrict__ g1,
                          const float* __restrict__ b1, const float* __restrict__ m1,
                          const float* __restrict__ v1, unsigned short* __restrict__ out,
                          int total) {
  int i = (blockIdx.x * blockDim.x + threadIdx.x) * 4;
  if (i >= total) {
    if (i < total + 64) *(ushort4v*)(out + i) = (ushort4v){0, 0, 0, 0};
    return;
  }
  float4 v = *(const float4*)(x + i);
  int c = i & 63;
  float4 g = *(const float4*)(g1 + c);
  float4 b = *(const float4*)(b1 + c);
  float4 m = *(const float4*)(m1 + c);
  float4 vv = *(const float4*)(v1 + c);
  ushort4v r;
  float sx = g.x * rsqrtf(vv.x + BN_EPS);
  float sy = g.y * rsqrtf(vv.y + BN_EPS);
  float sz = g.z * rsqrtf(vv.z + BN_EPS);
  float sw = g.w * rsqrtf(vv.w + BN_EPS);
  r.x = f2bf(silu_f((v.x - m.x) * sx + b.x));
  r.y = f2bf(silu_f((v.y - m.y) * sy + b.y));
  r.z = f2bf(silu_f((v.z - m.z) * sz + b.z));
  r.w = f2bf(silu_f((v.w - m.w) * sw + b.w));
  *(ushort4v*)(out + i) = r;
}

// ---- sparse conv: LDS triple-buffer + counted vmcnt + raw s_barrier (T3/T4).
// Block = 256 threads / 4 waves / 128 nodes. Iter k (fully unrolled, taps 0..26):
//   LDVG(k+4): 2 loads -> rv[(k+4)%3] (lane holds row for node lane&31 of its wave tile)
//   WLOAD(k+1): 4 loads -> wr[(k+1)&1]
//   s_waitcnt vmcnt(6): drains STAGE(k+1)+WLOAD(k)+older; leaves this iter's 6
//   s_barrier: all waves' STAGE(k+1) landed; all COMPUTE(k-1) reads done
//   STAGE(k+2) -> buf[(k+2)%3]  (post-barrier => WAR-safe: last reader was COMPUTE(k-1))
//   COMPUTE(k) on buf[k%3] with wr[k&1]
// STAGE is issued TWO iterations before consumption -> HBM-tail latency hidden.
// XOR swizzle (chunk ^= row&7) applied on the GLOBAL SRC side (LDS dest linear).
// MODE 0: epilogue = +bias, FiLM, bn2+silu -> bf16 a2 (block 0 zeroes a2 row N)
// MODE 1: epilogue = +bias + residual x -> f32 out
template <int MODE>
__global__ __launch_bounds__(256, 3) void conv_k(
    const unsigned short* __restrict__ act, const int* __restrict__ idx,
    const int* __restrict__ valid, const unsigned short* __restrict__ Wp,
    const float* __restrict__ bias,
    const float* __restrict__ scale_eff, const float* __restrict__ shift,
    const int* __restrict__ bidx,
    const float* __restrict__ g2, const float* __restrict__ b2,
    const float* __restrict__ m2, const float* __restrict__ v2,
    const float* __restrict__ xres,
    unsigned short* __restrict__ out_bf, float* __restrict__ out_f, int N) {
  __shared__ unsigned short lds[3][128 * 64];

  if (MODE == 0 && blockIdx.x == 0 && threadIdx.x < 64) {
    out_bf[(size_t)N * 64 + threadIdx.x] = 0;  // zero row for conv2's invalid taps
  }
  const int tid = threadIdx.x;
  const int lane = tid & 63;
  const int wid = tid >> 6;
  const int half = lane >> 5;   // 0/1
  const int r32 = lane & 31;
  const int n0 = blockIdx.x * 128;

  const int q0 = lane & 7;
  const int sg = lane >> 3;                 // 0..7: staging row subgroup
  const int srcq = q0 ^ sg;                 // pre-swizzled source chunk
  const int RH = wid >> 1;
  const int cb = wid & 1;
  const int nLV = min(n0 + wid * 32 + r32, N - 1);  // node whose rows this lane tracks

  f32x16 acc0, acc1;
#pragma unroll
  for (int i = 0; i < 16; ++i) { acc0[i] = 0.f; acc1[i] = 0.f; }

  short8 wrA[4], wrB[4];

#define LDVG(kk) \
    ((valid[(size_t)(kk) * N + nLV]) ? idx[(size_t)(kk) * N + nLV] : N)

#define WLOAD(kk, wr) do { \
    _Pragma("unroll") \
    for (int ks = 0; ks < 4; ++ks) \
      wr[ks] = ((const short8*)Wp)[((size_t)(kk) * 8 + ks * 2 + cb) * 64 + lane]; \
  } while (0)

  // lane stages 16B of row (wid*32 + i*8 + sg), phys chunk q0; source chunk srcq^... :
  // phys = logical ^ (row&7); row&7 = sg (i*8 keeps low 3 bits); lane's phys slot is q0
  // -> logical chunk fetched = q0 ^ sg = srcq.
#define STAGE(buf, rvreg) do { \
    _Pragma("unroll") \
    for (int i = 0; i < 4; ++i) { \
      int rg = __shfl(rvreg, i * 8 + sg); \
      const unsigned short* src = act + (size_t)rg * 64 + srcq * 8; \
      unsigned short* dst = &lds[buf][(wid * 32 + i * 8) * 64]; \
      gload_lds16(src, dst); \
    } } while (0)

  // fragment reads: logical chunk q = ks*2 + half of row R; phys p = q ^ (R&7); R&7 == r32&7
#define COMPUTE(buf, wr) do { \
    _Pragma("unroll") \
    for (int ks = 0; ks < 4; ++ks) { \
      int p = (ks * 2 + half) ^ (r32 & 7); \
      short8 a0v = *(const short8*)(&lds[buf][(RH * 64 + r32) * 64] + p * 8); \
      short8 a1v = *(const short8*)(&lds[buf][(RH * 64 + 32 + r32) * 64] + p * 8); \
      acc0 = __builtin_amdgcn_mfma_f32_32x32x16_bf16(a0v, wr[ks], acc0, 0, 0, 0); \
      acc1 = __builtin_amdgcn_mfma_f32_32x32x16_bf16(a1v, wr[ks], acc1, 0, 0, 0); \
    } } while (0)

  // prologue: rows 0..3, W(0), stage taps 0,1 (drained by iter-0's vmcnt(6))
  int t0 = LDVG(0);
  int t1 = LDVG(1);
  int rv0, rv1, rv2;
  rv2 = LDVG(2);      // rv[t%3] holds rows(t): tap2 -> rv2
  rv0 = LDVG(3);      // tap3 -> rv0
  rv1 = 0;
  WLOAD(0, wrA);
  STAGE(0, t0);
  STAGE(1, t1);

#pragma unroll
  for (int k = 0; k < KOFF; ++k) {
    if (k + 4 < KOFF) {
      int r = LDVG(k + 4);
      if ((k + 4) % 3 == 0) rv0 = r; else if ((k + 4) % 3 == 1) rv1 = r; else rv2 = r;
    }
    if (k + 1 < KOFF) {
      if ((k + 1) & 1) WLOAD(k + 1, wrB); else WLOAD(k + 1, wrA);
    }
    if (k <= 22)      { WAITV(6); }
    else if (k <= 25) { WAITV(4); }
    else              { WAITV(0); }
    __builtin_amdgcn_sched_barrier(0);
    __builtin_amdgcn_s_barrier();
    __builtin_amdgcn_sched_barrier(0);
    if (k + 2 < KOFF) {
      int rs = ((k + 2) % 3 == 0) ? rv0 : ((k + 2) % 3 == 1) ? rv1 : rv2;
      if ((k + 2) % 3 == 0)      STAGE(0, rs);
      else if ((k + 2) % 3 == 1) STAGE(1, rs);
      else                       STAGE(2, rs);
    }
    if (k % 3 == 0)      { if (k & 1) COMPUTE(0, wrB); else COMPUTE(0, wrA); }
    else if (k % 3 == 1) { if (k & 1) COMPUTE(1, wrB); else COMPUTE(1, wrA); }
    else                 { if (k & 1) COMPUTE(2, wrB); else COMPUTE(2, wrA); }
  }
#undef LDVG
#undef STAGE
#undef WLOAD
#undef COMPUTE

  // D frag: col = cb*32 + r32, row-in-subtile = (r&3) + 8*(r>>2) + 4*half
  if (MODE == 0) {
#pragma unroll
    for (int s = 0; s < 2; ++s) {
      f32x16 a = s ? acc1 : acc0;
      const int c = cb * 32 + r32;
      float bb = bias[c];
      float s2v = g2[c] * rsqrtf(v2[c] + BN_EPS);
      float o2v = b2[c] - m2[c] * s2v;
#pragma unroll
      for (int r = 0; r < 16; ++r) {
        int rowD = (r & 3) + 8 * (r >> 2) + 4 * half;
        int n = n0 + RH * 64 + s * 32 + rowD;
        if (n < N) {
          int bi = bidx[n];
          float h = a[r] + bb;
          h = scale_eff[bi * 64 + c] * h + shift[bi * 64 + c];
          float z = h * s2v + o2v;
          out_bf[(size_t)n * 64 + c] = f2bf(silu_f(z));
        }
      }
    }
  } else {
#pragma unroll
    for (int s = 0; s < 2; ++s) {
      f32x16 a = s ? acc1 : acc0;
      const int c = cb * 32 + r32;
      float bb = bias[c];
#pragma unroll
      for (int r = 0; r < 16; ++r) {
        int rowD = (r & 3) + 8 * (r >> 2) + 4 * half;
        int n = n0 + RH * 64 + s * 32 + rowD;
        if (n < N) {
          out_f[(size_t)n * 64 + c] = a[r] + bb + xres[(size_t)n * 64 + c];
        }
      }
    }
  }
}

extern "C" void kernel_launch(void* const* d_in, const int* in_sizes, int n_in,
                              void* d_out, int out_size, void* d_ws, size_t ws_size,
                              hipStream_t stream) {
  const float* x    = (const float*)d_in[0];
  const float* t    = (const float*)d_in[1];
  const int*   b    = (const int*)d_in[2];
  const int*   kidx = (const int*)d_in[3];
  const int*   kval = (const int*)d_in[4];
  const float* bn1g = (const float*)d_in[5];
  const float* bn1b = (const float*)d_in[6];
  const float* bn1m = (const float*)d_in[7];
  const float* bn1v = (const float*)d_in[8];
  const float* W1   = (const float*)d_in[9];
  const float* b1c  = (const float*)d_in[10];
  const float* bn2g = (const float*)d_in[11];
  const float* bn2b = (const float*)d_in[12];
  const float* bn2m = (const float*)d_in[13];
  const float* bn2v = (const float*)d_in[14];
  const float* W2   = (const float*)d_in[15];
  const float* b2c  = (const float*)d_in[16];
  const float* Wt   = (const float*)d_in[17];
  const float* bt   = (const float*)d_in[18];
  float* out = (float*)d_out;

  const int N = in_sizes[2];        // 100000
  const int total = N * 64;

  // workspace layout (bytes); act buffers have N+1 rows (row N = zeros)
  char* ws = (char*)d_ws;
  size_t actB = ((size_t)(N + 1) * 64 * 2 + 255) & ~(size_t)255;
  unsigned short* a1bf = (unsigned short*)ws;
  unsigned short* a2bf = (unsigned short*)(ws + actB);
  const size_t wpackB = (size_t)KOFF * 4 * 2 * 64 * 8 * 2;  // 221184 B
  unsigned short* W1p = (unsigned short*)(ws + 2 * actB);
  unsigned short* W2p = (unsigned short*)(ws + 2 * actB + wpackB);
  float* scale_eff = (float*)(ws + 2 * actB + 2 * wpackB);
  float* shiftp    = scale_eff + 16 * 64;

  time_mlp<<<8, 256, 0, stream>>>(t, Wt, bt, scale_eff, shiftp);
  const int wtot = KOFF * 4 * 2 * 64 * 8;
  pack_w32<<<(2 * wtot + 255) / 256, 256, 0, stream>>>(W1, W2, W1p, W2p);
  bn_silu_k<<<(total / 4 + 16 + 255) / 256, 256, 0, stream>>>(x, bn1g, bn1b, bn1m,
                                                              bn1v, a1bf, total);

  int nblk = (N + 127) / 128;
  conv_k<0><<<nblk, 256, 0, stream>>>(a1bf, kidx, kval, W1p, b1c, scale_eff,
                                      shiftp, b, bn2g, bn2b, bn2m, bn2v,
                                      nullptr, a2bf, nullptr, N);
  conv_k<1><<<nblk, 256, 0, stream>>>(a2bf, kidx, kval, W2p, b2c, nullptr, nullptr,
                                      nullptr, nullptr, nullptr, nullptr, nullptr,
                                      x, nullptr, out, N);
}

// Round 9
// 143.472 us; speedup vs baseline: 1.1522x; 1.1522x over previous
//
#include <hip/hip_runtime.h>

typedef __attribute__((ext_vector_type(8))) short short8;
typedef __attribute__((ext_vector_type(16))) float f32x16;
typedef __attribute__((ext_vector_type(4))) unsigned short ushort4v;

#define BN_EPS 1e-5f
#define KOFF 27

static __device__ __forceinline__ unsigned short f2bf(float f) {
  unsigned int u = __float_as_uint(f);
  u += 0x7fffu + ((u >> 16) & 1u);
  return (unsigned short)(u >> 16);
}

static __device__ __forceinline__ float silu_f(float z) {
  return z / (1.f + __expf(-z));
}

// ---- time embedding MLP: tp = silu(t) @ Wt + bt; store (1+scale), shift
__global__ void time_mlp(const float* __restrict__ t, const float* __restrict__ Wt,
                         const float* __restrict__ bt,
                         float* __restrict__ scale_eff, float* __restrict__ shift) {
  int tid = blockIdx.x * blockDim.x + threadIdx.x; // 2048 = 16 batches * 128 out
  int bi = tid >> 7, co = tid & 127;
  float acc = bt[co];
  for (int e = 0; e < 256; ++e) {
    float tv = t[bi * 256 + e];
    acc += silu_f(tv) * Wt[e * 128 + co];
  }
  if (co < 64) scale_eff[bi * 64 + co] = 1.f + acc;
  else         shift[bi * 64 + (co - 64)] = acc;
}

// ---- pack W1 and W2 [k, ci, co] (f32) into bf16 MFMA B-fragment order (32x32x16).
// Fragment f = k*8 + ks*2 + cb : lane l elem j <- W[k][ks*16 + (l>>5)*8 + j][cb*32 + (l&31)]
__global__ void pack_w32(const float* __restrict__ W1, const float* __restrict__ W2,
                         unsigned short* __restrict__ Wp1, unsigned short* __restrict__ Wp2) {
  const int tot = KOFF * 4 * 2 * 64 * 8;
  int tid = blockIdx.x * blockDim.x + threadIdx.x;
  const float* W = W1;
  unsigned short* Wp = Wp1;
  if (tid >= tot) { tid -= tot; W = W2; Wp = Wp2; }
  if (tid >= tot) return;
  int j = tid & 7, lane = (tid >> 3) & 63, cb = (tid >> 9) & 1, ks = (tid >> 10) & 3, k = tid >> 12;
  int ci = ks * 16 + (lane >> 5) * 8 + j;
  int co = cb * 32 + (lane & 31);
  Wp[tid] = f2bf(W[(k * 64 + ci) * 64 + co]);
}

// ---- a1 = bf16(silu(bn1(x))), bn1 affine computed inline; tail threads zero row N
__global__ void bn_silu_k(const float* __restrict__ x, const float* __restrict__ g1,
                          const float* __restrict__ b1, const float* __restrict__ m1,
                          const float* __restrict__ v1, unsigned short* __restrict__ out,
                          int total) {
  int i = (blockIdx.x * blockDim.x + threadIdx.x) * 4;
  if (i >= total) {
    if (i < total + 64) *(ushort4v*)(out + i) = (ushort4v){0, 0, 0, 0};
    return;
  }
  float4 v = *(const float4*)(x + i);
  int c = i & 63;
  float4 g = *(const float4*)(g1 + c);
  float4 b = *(const float4*)(b1 + c);
  float4 m = *(const float4*)(m1 + c);
  float4 vv = *(const float4*)(v1 + c);
  ushort4v r;
  float sx = g.x * rsqrtf(vv.x + BN_EPS);
  float sy = g.y * rsqrtf(vv.y + BN_EPS);
  float sz = g.z * rsqrtf(vv.z + BN_EPS);
  float sw = g.w * rsqrtf(vv.w + BN_EPS);
  r.x = f2bf(silu_f((v.x - m.x) * sx + b.x));
  r.y = f2bf(silu_f((v.y - m.y) * sy + b.y));
  r.z = f2bf(silu_f((v.z - m.z) * sz + b.z));
  r.w = f2bf(silu_f((v.w - m.w) * sw + b.w));
  *(ushort4v*)(out + i) = r;
}

// ---- sparse conv: reg-staged gather (T14) + raw barrier (lgkmcnt-only, NO vmcnt drain).
// Block = 256 threads / 4 waves / 128 nodes. Double-buffered 16KB LDS tiles.
// Pipeline at iter k (fully unrolled):
//   DSWRITE(k+1): staged regs -> buf[(k+1)&1]  (WAR-safe: that buf was read at k-1, barrier between)
//   GLOAD(k+2): global -> regs st[k&1] (rows from rg[k&1], LDVG'd at iter k-1)
//   LDVG(k+3): valid/idx -> rg[(k+1)&1]
//   WLOAD(k+1): W frags -> wr[(k+1)&1]
//   COMPUTE(k): ds_read buf[k&1] + 8 MFMA with wr[k&1]
//   s_waitcnt lgkmcnt(0); s_barrier      <- vmcnt NOT drained; in-flight loads cross in regs
// LDS write-side swizzle: phys chunk = q0 ^ (row&7); reads use p = (ks*2+half)^(r32&7).
// Both are 2-way bank aliases (free, m136). Global reads linear.
// MODE 0: epilogue = +bias, FiLM, bn2+silu -> bf16 a2 (block 0 zeroes a2 row N)
// MODE 1: epilogue = +bias + residual x -> f32 out
template <int MODE>
__global__ __launch_bounds__(256, 3) void conv_k(
    const unsigned short* __restrict__ act, const int* __restrict__ idx,
    const int* __restrict__ valid, const unsigned short* __restrict__ Wp,
    const float* __restrict__ bias,
    const float* __restrict__ scale_eff, const float* __restrict__ shift,
    const int* __restrict__ bidx,
    const float* __restrict__ g2, const float* __restrict__ b2,
    const float* __restrict__ m2, const float* __restrict__ v2,
    const float* __restrict__ xres,
    unsigned short* __restrict__ out_bf, float* __restrict__ out_f, int N) {
  __shared__ unsigned short lds[2][128 * 64];

  if (MODE == 0 && blockIdx.x == 0 && threadIdx.x < 64) {
    out_bf[(size_t)N * 64 + threadIdx.x] = 0;  // zero row for conv2's invalid taps
  }
  const int tid = threadIdx.x;
  const int lane = tid & 63;
  const int wid = tid >> 6;
  const int half = lane >> 5;   // 0/1
  const int r32 = lane & 31;
  const int n0 = blockIdx.x * 128;

  const int q0 = lane & 7;      // chunk this lane stages
  const int sg = lane >> 3;     // row-subgroup 0..7
  const int RH = wid >> 1;
  const int cb = wid & 1;

  f32x16 acc0, acc1;
#pragma unroll
  for (int i = 0; i < 16; ++i) { acc0[i] = 0.f; acc1[i] = 0.f; }

  int rgA[4], rgB[4];        // gather rows, tap-parity sets
  short8 stA[4], stB[4];     // staged row chunks (16B each)
  short8 wrA[4], wrB[4];     // W fragments

  // thread's staged rows: rows(i) = wid*32 + i*8 + sg  (i=0..3)
#define LDVG(kk, rg) do { \
    _Pragma("unroll") \
    for (int i = 0; i < 4; ++i) { \
      int node = min(n0 + wid * 32 + i * 8 + sg, N - 1); \
      int v = valid[(size_t)(kk) * N + node]; \
      int g = idx[(size_t)(kk) * N + node]; \
      rg[i] = v ? g : N; \
    } } while (0)

#define GLOAD(st, rg) do { \
    _Pragma("unroll") \
    for (int i = 0; i < 4; ++i) \
      st[i] = *(const short8*)(act + (size_t)rg[i] * 64 + q0 * 8); \
  } while (0)

  // phys chunk = q0 ^ (row&7) = q0 ^ sg
#define DSWRITE(buf, st) do { \
    _Pragma("unroll") \
    for (int i = 0; i < 4; ++i) \
      *(short8*)(&lds[buf][(wid * 32 + i * 8 + sg) * 64 + (q0 ^ sg) * 8]) = st[i]; \
  } while (0)

#define WLOAD(kk, wr) do { \
    _Pragma("unroll") \
    for (int ks = 0; ks < 4; ++ks) \
      wr[ks] = ((const short8*)Wp)[((size_t)(kk) * 8 + ks * 2 + cb) * 64 + lane]; \
  } while (0)

  // read phys p = (ks*2 + half) ^ (row&7); row&7 == r32&7 for both sub-tiles
#define COMPUTE(buf, wr) do { \
    _Pragma("unroll") \
    for (int ks = 0; ks < 4; ++ks) { \
      int p = (ks * 2 + half) ^ (r32 & 7); \
      short8 a0v = *(const short8*)(&lds[buf][(RH * 64 + r32) * 64] + p * 8); \
      short8 a1v = *(const short8*)(&lds[buf][(RH * 64 + 32 + r32) * 64] + p * 8); \
      acc0 = __builtin_amdgcn_mfma_f32_32x32x16_bf16(a0v, wr[ks], acc0, 0, 0, 0); \
      acc1 = __builtin_amdgcn_mfma_f32_32x32x16_bf16(a1v, wr[ks], acc1, 0, 0, 0); \
    } } while (0)

#define BARRIER() do { \
    asm volatile("s_waitcnt lgkmcnt(0)" ::: "memory"); \
    __builtin_amdgcn_s_barrier(); \
  } while (0)

  // prologue
  LDVG(0, rgA);
  LDVG(1, rgB);
  GLOAD(stA, rgA);        // tap 0 -> stA
  GLOAD(stB, rgB);        // tap 1 -> stB
  LDVG(2, rgA);           // rows(2) (consumed by GLOAD at iter 0)
  WLOAD(0, wrA);
  DSWRITE(0, stA);        // buf0 <- tap 0 (compiler waits stA's vmcnt here)
  BARRIER();

#pragma unroll
  for (int k = 0; k < KOFF; ++k) {
    if (k + 1 < KOFF) {
      if ((k + 1) & 1) DSWRITE(1, stB); else DSWRITE(0, stA);
    }
    if (k + 2 < KOFF) {
      if (k & 1) GLOAD(stB, rgB); else GLOAD(stA, rgA);   // tap k+2 -> st[k&1], rows in rg[k&1]
    }
    if (k + 3 < KOFF) {
      if ((k + 1) & 1) LDVG(k + 3, rgB); else LDVG(k + 3, rgA);  // rows(k+3) -> rg[(k+1)&1]
    }
    if (k + 1 < KOFF) {
      if ((k + 1) & 1) WLOAD(k + 1, wrB); else WLOAD(k + 1, wrA);
    }
    if (k & 1) COMPUTE(1, wrB); else COMPUTE(0, wrA);
    if (k + 1 < KOFF) BARRIER();
  }
#undef LDVG
#undef GLOAD
#undef DSWRITE
#undef WLOAD
#undef COMPUTE
#undef BARRIER

  // D frag: col = cb*32 + r32, row-in-subtile = (r&3) + 8*(r>>2) + 4*half
  if (MODE == 0) {
#pragma unroll
    for (int s = 0; s < 2; ++s) {
      f32x16 a = s ? acc1 : acc0;
      const int c = cb * 32 + r32;
      float bb = bias[c];
      float s2v = g2[c] * rsqrtf(v2[c] + BN_EPS);
      float o2v = b2[c] - m2[c] * s2v;
#pragma unroll
      for (int r = 0; r < 16; ++r) {
        int rowD = (r & 3) + 8 * (r >> 2) + 4 * half;
        int n = n0 + RH * 64 + s * 32 + rowD;
        if (n < N) {
          int bi = bidx[n];
          float h = a[r] + bb;
          h = scale_eff[bi * 64 + c] * h + shift[bi * 64 + c];
          float z = h * s2v + o2v;
          out_bf[(size_t)n * 64 + c] = f2bf(silu_f(z));
        }
      }
    }
  } else {
#pragma unroll
    for (int s = 0; s < 2; ++s) {
      f32x16 a = s ? acc1 : acc0;
      const int c = cb * 32 + r32;
      float bb = bias[c];
#pragma unroll
      for (int r = 0; r < 16; ++r) {
        int rowD = (r & 3) + 8 * (r >> 2) + 4 * half;
        int n = n0 + RH * 64 + s * 32 + rowD;
        if (n < N) {
          out_f[(size_t)n * 64 + c] = a[r] + bb + xres[(size_t)n * 64 + c];
        }
      }
    }
  }
}

extern "C" void kernel_launch(void* const* d_in, const int* in_sizes, int n_in,
                              void* d_out, int out_size, void* d_ws, size_t ws_size,
                              hipStream_t stream) {
  const float* x    = (const float*)d_in[0];
  const float* t    = (const float*)d_in[1];
  const int*   b    = (const int*)d_in[2];
  const int*   kidx = (const int*)d_in[3];
  const int*   kval = (const int*)d_in[4];
  const float* bn1g = (const float*)d_in[5];
  const float* bn1b = (const float*)d_in[6];
  const float* bn1m = (const float*)d_in[7];
  const float* bn1v = (const float*)d_in[8];
  const float* W1   = (const float*)d_in[9];
  const float* b1c  = (const float*)d_in[10];
  const float* bn2g = (const float*)d_in[11];
  const float* bn2b = (const float*)d_in[12];
  const float* bn2m = (const float*)d_in[13];
  const float* bn2v = (const float*)d_in[14];
  const float* W2   = (const float*)d_in[15];
  const float* b2c  = (const float*)d_in[16];
  const float* Wt   = (const float*)d_in[17];
  const float* bt   = (const float*)d_in[18];
  float* out = (float*)d_out;

  const int N = in_sizes[2];        // 100000
  const int total = N * 64;

  // workspace layout (bytes); act buffers have N+1 rows (row N = zeros)
  char* ws = (char*)d_ws;
  size_t actB = ((size_t)(N + 1) * 64 * 2 + 255) & ~(size_t)255;
  unsigned short* a1bf = (unsigned short*)ws;
  unsigned short* a2bf = (unsigned short*)(ws + actB);
  const size_t wpackB = (size_t)KOFF * 4 * 2 * 64 * 8 * 2;  // 221184 B
  unsigned short* W1p = (unsigned short*)(ws + 2 * actB);
  unsigned short* W2p = (unsigned short*)(ws + 2 * actB + wpackB);
  float* scale_eff = (float*)(ws + 2 * actB + 2 * wpackB);
  float* shiftp    = scale_eff + 16 * 64;

  time_mlp<<<8, 256, 0, stream>>>(t, Wt, bt, scale_eff, shiftp);
  const int wtot = KOFF * 4 * 2 * 64 * 8;
  pack_w32<<<(2 * wtot + 255) / 256, 256, 0, stream>>>(W1, W2, W1p, W2p);
  bn_silu_k<<<(total / 4 + 16 + 255) / 256, 256, 0, stream>>>(x, bn1g, bn1b, bn1m,
                                                              bn1v, a1bf, total);

  int nblk = (N + 127) / 128;
  conv_k<0><<<nblk, 256, 0, stream>>>(a1bf, kidx, kval, W1p, b1c, scale_eff,
                                      shiftp, b, bn2g, bn2b, bn2m, bn2v,
                                      nullptr, a2bf, nullptr, N);
  conv_k<1><<<nblk, 256, 0, stream>>>(a2bf, kidx, kval, W2p, b2c, nullptr, nullptr,
                                      nullptr, nullptr, nullptr, nullptr, nullptr,
                                      x, nullptr, out, N);
}

// Round 10
// 131.736 us; speedup vs baseline: 1.2548x; 1.0891x over previous
//
#include <hip/hip_runtime.h>

typedef __attribute__((ext_vector_type(8))) short short8;
typedef __attribute__((ext_vector_type(16))) float f32x16;
typedef __attribute__((ext_vector_type(4))) unsigned short ushort4v;

#define BN_EPS 1e-5f
#define KOFF 27

static __device__ __forceinline__ unsigned short f2bf(float f) {
  unsigned int u = __float_as_uint(f);
  u += 0x7fffu + ((u >> 16) & 1u);
  return (unsigned short)(u >> 16);
}

static __device__ __forceinline__ float silu_f(float z) {
  return z / (1.f + __expf(-z));
}

// ---- fused prep: [0,864) pack W1+W2, [864,872) time MLP, [872,...) bn1+silu
// pack: W[k, ci, co] (f32) -> bf16 MFMA B-fragment order (32x32x16).
// Fragment f = k*8 + ks*2 + cb : lane l elem j <- W[k][ks*16 + (l>>5)*8 + j][cb*32 + (l&31)]
__global__ void prep_all(const float* __restrict__ t, const float* __restrict__ Wt,
                         const float* __restrict__ bt,
                         float* __restrict__ scale_eff, float* __restrict__ shift,
                         const float* __restrict__ W1, const float* __restrict__ W2,
                         unsigned short* __restrict__ Wp1, unsigned short* __restrict__ Wp2,
                         const float* __restrict__ x, const float* __restrict__ g1,
                         const float* __restrict__ b1, const float* __restrict__ m1,
                         const float* __restrict__ v1, unsigned short* __restrict__ a1bf,
                         int total) {
  const int bid = blockIdx.x;
  if (bid < 864) {
    int tid = bid * 256 + threadIdx.x;          // 0 .. 221183 = 2*tot
    const int tot = KOFF * 4 * 2 * 64 * 8;
    const float* W = W1;
    unsigned short* Wp = Wp1;
    if (tid >= tot) { tid -= tot; W = W2; Wp = Wp2; }
    int j = tid & 7, lane = (tid >> 3) & 63, cbb = (tid >> 9) & 1,
        ks = (tid >> 10) & 3, k = tid >> 12;
    int ci = ks * 16 + (lane >> 5) * 8 + j;
    int co = cbb * 32 + (lane & 31);
    Wp[tid] = f2bf(W[(k * 64 + ci) * 64 + co]);
  } else if (bid < 872) {
    int tid = (bid - 864) * 256 + threadIdx.x;  // 0..2047 = 16 batches * 128 out
    int bi = tid >> 7, co = tid & 127;
    float acc = bt[co];
    for (int e = 0; e < 256; ++e) {
      float tv = t[bi * 256 + e];
      acc += silu_f(tv) * Wt[e * 128 + co];
    }
    if (co < 64) scale_eff[bi * 64 + co] = 1.f + acc;
    else         shift[bi * 64 + (co - 64)] = acc;
  } else {
    int i = ((bid - 872) * 256 + threadIdx.x) * 4;
    if (i >= total) {
      if (i < total + 64) *(ushort4v*)(a1bf + i) = (ushort4v){0, 0, 0, 0};
      return;
    }
    float4 v = *(const float4*)(x + i);
    int c = i & 63;
    float4 g = *(const float4*)(g1 + c);
    float4 b = *(const float4*)(b1 + c);
    float4 m = *(const float4*)(m1 + c);
    float4 vv = *(const float4*)(v1 + c);
    ushort4v r;
    float sx = g.x * rsqrtf(vv.x + BN_EPS);
    float sy = g.y * rsqrtf(vv.y + BN_EPS);
    float sz = g.z * rsqrtf(vv.z + BN_EPS);
    float sw = g.w * rsqrtf(vv.w + BN_EPS);
    r.x = f2bf(silu_f((v.x - m.x) * sx + b.x));
    r.y = f2bf(silu_f((v.y - m.y) * sy + b.y));
    r.z = f2bf(silu_f((v.z - m.z) * sz + b.z));
    r.w = f2bf(silu_f((v.w - m.w) * sw + b.w));
    *(ushort4v*)(a1bf + i) = r;
  }
}

// ---- sparse conv: 64-node tile, reg-staged gather + raw barrier (lgkmcnt-only).
// Block = 256 threads / 4 waves / 64 nodes; grid ~1563 blocks -> ~6 blocks/CU.
// Wave w: rows (w>>1)*32..+31, cols (w&1)*32..+31 -> ONE f32x16 accumulator.
// Staging: thread stages rows wid*16 + i*8 + sg (i=0..1), chunk q0 (16B).
// Double-buffered 8KB LDS tiles; write-side XOR swizzle phys = q0 ^ (row&7);
// read phys p = (ks*2+half) ^ (r32&7). Pipeline at iter k (fully unrolled):
//   DSWRITE(k+1) ; GLOAD(k+2)->st[k&1] ; LDVG(k+3)->rg[(k+1)&1] ; WLOAD(k+1) ;
//   COMPUTE(k) ; s_waitcnt lgkmcnt(0); s_barrier   (vmcnt NOT drained)
// MODE 0: epilogue = +bias, FiLM, bn2+silu -> bf16 a2 (block 0 zeroes a2 row N)
// MODE 1: epilogue = +bias + residual x -> f32 out
template <int MODE>
__global__ __launch_bounds__(256, 6) void conv_k(
    const unsigned short* __restrict__ act, const int* __restrict__ idx,
    const int* __restrict__ valid, const unsigned short* __restrict__ Wp,
    const float* __restrict__ bias,
    const float* __restrict__ scale_eff, const float* __restrict__ shift,
    const int* __restrict__ bidx,
    const float* __restrict__ g2, const float* __restrict__ b2,
    const float* __restrict__ m2, const float* __restrict__ v2,
    const float* __restrict__ xres,
    unsigned short* __restrict__ out_bf, float* __restrict__ out_f, int N) {
  __shared__ unsigned short lds[2][64 * 64];

  if (MODE == 0 && blockIdx.x == 0 && threadIdx.x < 64) {
    out_bf[(size_t)N * 64 + threadIdx.x] = 0;  // zero row for conv2's invalid taps
  }
  const int tid = threadIdx.x;
  const int lane = tid & 63;
  const int wid = tid >> 6;
  const int half = lane >> 5;   // 0/1
  const int r32 = lane & 31;
  const int n0 = blockIdx.x * 64;

  const int q0 = lane & 7;      // chunk this lane stages
  const int sg = lane >> 3;     // row-subgroup 0..7
  const int RH = wid >> 1;
  const int cb = wid & 1;

  f32x16 acc;
#pragma unroll
  for (int i = 0; i < 16; ++i) acc[i] = 0.f;

  int rgA[2], rgB[2];        // gather rows, tap-parity sets
  short8 stA[2], stB[2];     // staged row chunks (16B each)
  short8 wrA[4], wrB[4];     // W fragments

  // thread's staged rows: rows(i) = wid*16 + i*8 + sg  (i=0..1)
#define LDVG(kk, rg) do { \
    _Pragma("unroll") \
    for (int i = 0; i < 2; ++i) { \
      int node = min(n0 + wid * 16 + i * 8 + sg, N - 1); \
      int v = valid[(size_t)(kk) * N + node]; \
      int g = idx[(size_t)(kk) * N + node]; \
      rg[i] = v ? g : N; \
    } } while (0)

#define GLOAD(st, rg) do { \
    _Pragma("unroll") \
    for (int i = 0; i < 2; ++i) \
      st[i] = *(const short8*)(act + (size_t)rg[i] * 64 + q0 * 8); \
  } while (0)

  // phys chunk = q0 ^ (row&7) = q0 ^ sg
#define DSWRITE(buf, st) do { \
    _Pragma("unroll") \
    for (int i = 0; i < 2; ++i) \
      *(short8*)(&lds[buf][(wid * 16 + i * 8 + sg) * 64 + (q0 ^ sg) * 8]) = st[i]; \
  } while (0)

#define WLOAD(kk, wr) do { \
    _Pragma("unroll") \
    for (int ks = 0; ks < 4; ++ks) \
      wr[ks] = ((const short8*)Wp)[((size_t)(kk) * 8 + ks * 2 + cb) * 64 + lane]; \
  } while (0)

  // read phys p = (ks*2 + half) ^ (row&7); row&7 == r32&7
#define COMPUTE(buf, wr) do { \
    _Pragma("unroll") \
    for (int ks = 0; ks < 4; ++ks) { \
      int p = (ks * 2 + half) ^ (r32 & 7); \
      short8 av = *(const short8*)(&lds[buf][(RH * 32 + r32) * 64] + p * 8); \
      acc = __builtin_amdgcn_mfma_f32_32x32x16_bf16(av, wr[ks], acc, 0, 0, 0); \
    } } while (0)

#define BARRIER() do { \
    asm volatile("s_waitcnt lgkmcnt(0)" ::: "memory"); \
    __builtin_amdgcn_s_barrier(); \
  } while (0)

  // prologue
  LDVG(0, rgA);
  LDVG(1, rgB);
  GLOAD(stA, rgA);        // tap 0 -> stA
  GLOAD(stB, rgB);        // tap 1 -> stB
  LDVG(2, rgA);           // rows(2) (consumed by GLOAD at iter 0)
  WLOAD(0, wrA);
  DSWRITE(0, stA);        // buf0 <- tap 0 (compiler waits stA's vmcnt here)
  BARRIER();

#pragma unroll
  for (int k = 0; k < KOFF; ++k) {
    if (k + 1 < KOFF) {
      if ((k + 1) & 1) DSWRITE(1, stB); else DSWRITE(0, stA);
    }
    if (k + 2 < KOFF) {
      if (k & 1) GLOAD(stB, rgB); else GLOAD(stA, rgA);   // tap k+2 -> st[k&1]
    }
    if (k + 3 < KOFF) {
      if ((k + 1) & 1) LDVG(k + 3, rgB); else LDVG(k + 3, rgA);
    }
    if (k + 1 < KOFF) {
      if ((k + 1) & 1) WLOAD(k + 1, wrB); else WLOAD(k + 1, wrA);
    }
    if (k & 1) COMPUTE(1, wrB); else COMPUTE(0, wrA);
    if (k + 1 < KOFF) BARRIER();
  }
#undef LDVG
#undef GLOAD
#undef DSWRITE
#undef WLOAD
#undef COMPUTE
#undef BARRIER

  // D frag: col = cb*32 + r32, row = RH*32 + (r&3) + 8*(r>>2) + 4*half
  if (MODE == 0) {
    const int c = cb * 32 + r32;
    float bb = bias[c];
    float s2v = g2[c] * rsqrtf(v2[c] + BN_EPS);
    float o2v = b2[c] - m2[c] * s2v;
#pragma unroll
    for (int r = 0; r < 16; ++r) {
      int rowD = (r & 3) + 8 * (r >> 2) + 4 * half;
      int n = n0 + RH * 32 + rowD;
      if (n < N) {
        int bi = bidx[n];
        float h = acc[r] + bb;
        h = scale_eff[bi * 64 + c] * h + shift[bi * 64 + c];
        float z = h * s2v + o2v;
        out_bf[(size_t)n * 64 + c] = f2bf(silu_f(z));
      }
    }
  } else {
    const int c = cb * 32 + r32;
    float bb = bias[c];
#pragma unroll
    for (int r = 0; r < 16; ++r) {
      int rowD = (r & 3) + 8 * (r >> 2) + 4 * half;
      int n = n0 + RH * 32 + rowD;
      if (n < N) {
        out_f[(size_t)n * 64 + c] = acc[r] + bb + xres[(size_t)n * 64 + c];
      }
    }
  }
}

extern "C" void kernel_launch(void* const* d_in, const int* in_sizes, int n_in,
                              void* d_out, int out_size, void* d_ws, size_t ws_size,
                              hipStream_t stream) {
  const float* x    = (const float*)d_in[0];
  const float* t    = (const float*)d_in[1];
  const int*   b    = (const int*)d_in[2];
  const int*   kidx = (const int*)d_in[3];
  const int*   kval = (const int*)d_in[4];
  const float* bn1g = (const float*)d_in[5];
  const float* bn1b = (const float*)d_in[6];
  const float* bn1m = (const float*)d_in[7];
  const float* bn1v = (const float*)d_in[8];
  const float* W1   = (const float*)d_in[9];
  const float* b1c  = (const float*)d_in[10];
  const float* bn2g = (const float*)d_in[11];
  const float* bn2b = (const float*)d_in[12];
  const float* bn2m = (const float*)d_in[13];
  const float* bn2v = (const float*)d_in[14];
  const float* W2   = (const float*)d_in[15];
  const float* b2c  = (const float*)d_in[16];
  const float* Wt   = (const float*)d_in[17];
  const float* bt   = (const float*)d_in[18];
  float* out = (float*)d_out;

  const int N = in_sizes[2];        // 100000
  const int total = N * 64;

  // workspace layout (bytes); act buffers have N+1 rows (row N = zeros)
  char* ws = (char*)d_ws;
  size_t actB = ((size_t)(N + 1) * 64 * 2 + 255) & ~(size_t)255;
  unsigned short* a1bf = (unsigned short*)ws;
  unsigned short* a2bf = (unsigned short*)(ws + actB);
  const size_t wpackB = (size_t)KOFF * 4 * 2 * 64 * 8 * 2;  // 221184 B
  unsigned short* W1p = (unsigned short*)(ws + 2 * actB);
  unsigned short* W2p = (unsigned short*)(ws + 2 * actB + wpackB);
  float* scale_eff = (float*)(ws + 2 * actB + 2 * wpackB);
  float* shiftp    = scale_eff + 16 * 64;

  // fused prep: 864 pack blocks + 8 mlp blocks + bn_silu blocks
  int bnblk = (total / 4 + 16 + 255) / 256;
  prep_all<<<872 + bnblk, 256, 0, stream>>>(t, Wt, bt, scale_eff, shiftp,
                                            W1, W2, W1p, W2p,
                                            x, bn1g, bn1b, bn1m, bn1v, a1bf, total);

  int nblk = (N + 63) / 64;
  conv_k<0><<<nblk, 256, 0, stream>>>(a1bf, kidx, kval, W1p, b1c, scale_eff,
                                      shiftp, b, bn2g, bn2b, bn2m, bn2v,
                                      nullptr, a2bf, nullptr, N);
  conv_k<1><<<nblk, 256, 0, stream>>>(a2bf, kidx, kval, W2p, b2c, nullptr, nullptr,
                                      nullptr, nullptr, nullptr, nullptr, nullptr,
                                      x, nullptr, out, N);
}